// Round 13
// baseline (232.662 us; speedup 1.0000x reference)
//
#include <hip/hip_runtime.h>

typedef unsigned short u16;
typedef __attribute__((ext_vector_type(8))) short short8v;
typedef __attribute__((ext_vector_type(4))) float floatx4;

#define B_ 16
#define C_ 512
#define N_ 4096
#define K_ 128   // keys

__device__ __forceinline__ float bf2f(u16 u) {
    unsigned int x = ((unsigned int)u) << 16;
    return __builtin_bit_cast(float, x);
}
__device__ __forceinline__ u16 f2bf(float f) {
    unsigned int u = __builtin_bit_cast(unsigned int, f);
    u = u + 0x7FFFu + ((u >> 16) & 1u);
    return (u16)(u >> 16);
}
// async global(16B) -> LDS, wave-uniform dest base + lane*16
__device__ __forceinline__ void gload_lds16(const u16* g, u16* l) {
    __builtin_amdgcn_global_load_lds(
        (const __attribute__((address_space(1))) void*)g,
        (__attribute__((address_space(3))) void*)l, 16, 0, 0);
}

// counted-vmcnt barrier: VMC newest vmem ops stay in flight across the barrier;
// everything older (incl. the KLDS for the buffer consumed next) is drained.
#define BARRIER_VM(VMC) do { \
    asm volatile("s_waitcnt vmcnt(" #VMC ") lgkmcnt(0)" ::: "memory"); \
    __builtin_amdgcn_s_barrier(); \
    __builtin_amdgcn_sched_barrier(0); \
} while (0)

// ---------------------------------------------------------------------------
// P0: fp32 -> bf16 converts (y1,y2,wk1,wk2,wv1,wv2) + wq transpose, one launch
// ---------------------------------------------------------------------------
__global__ void conv_all(const float* __restrict__ y1, const float* __restrict__ y2,
                         const float* __restrict__ wk1, const float* __restrict__ wk2,
                         const float* __restrict__ wv1, const float* __restrict__ wv2,
                         const float* __restrict__ wq1, const float* __restrict__ wq2,
                         u16* y1b, u16* y2b, u16* wk1b, u16* wk2b, u16* wv1b, u16* wv2b,
                         u16* wq1t, u16* wq2t) {
    int tid = blockIdx.x * 256 + threadIdx.x;
    const int SY = B_ * K_ * C_;        // 1048576
    const int SWK = 256 * 512;          // 131072
    const int SWV = 512 * 512;          // 262144
    const int SQ = 128 * 512;           // 65536
    int base = 2*SY + 2*SWK + 2*SWV;
    if (tid < base) {
        const float* src; u16* dst; int off;
        if (tid < SY)                 { src = y1;  dst = y1b;  off = tid; }
        else if (tid < 2*SY)          { src = y2;  dst = y2b;  off = tid - SY; }
        else if (tid < 2*SY+SWK)      { src = wk1; dst = wk1b; off = tid - 2*SY; }
        else if (tid < 2*SY+2*SWK)    { src = wk2; dst = wk2b; off = tid - 2*SY - SWK; }
        else if (tid < 2*SY+2*SWK+SWV){ src = wv1; dst = wv1b; off = tid - 2*SY - 2*SWK; }
        else                          { src = wv2; dst = wv2b; off = tid - 2*SY - 2*SWK - SWV; }
        dst[off] = f2bf(src[off]);
    } else {
        int e = tid - base;           // 0 .. 2*SQ-1
        const float* s = (e >= SQ) ? wq2 : wq1;
        u16* d = (e >= SQ) ? wq2t : wq1t;
        e &= (SQ - 1);
        int dd = e >> 9;              // 0..127
        int c = e & 511;              // coalesced read over c
        d[c * 128 + dd] = f2bf(s[dd * 512 + c]);
    }
}

// ---------------------------------------------------------------------------
// P1: k1b/k2b [b][key][256] = y @ wk^T + bk  AND  vt1/vt2 [b][c][128] = (y@wv^T+bv)^T
// ---------------------------------------------------------------------------
__global__ void gemm_gkgv(const u16* __restrict__ y1b, const u16* __restrict__ y2b,
                          const u16* __restrict__ wk1b, const u16* __restrict__ wk2b,
                          const u16* __restrict__ wv1b, const u16* __restrict__ wv2b,
                          const float* __restrict__ bk1, const float* __restrict__ bk2,
                          const float* __restrict__ bv1, const float* __restrict__ bv2,
                          u16* k1b, u16* k2b, u16* vt1, u16* vt2) {
    int l = threadIdx.x;
    int id = blockIdx.x;
    const u16 *A, *Bt; const float* bias; u16* outp;
    int m0, n0, po; bool bias_m;
    if (id < 256) {
        int bx = id & 1, by = (id >> 1) & 3, z = id >> 3;
        int b = z >> 1, which = z & 1;
        A = (which ? y2b : y1b) + (size_t)b * K_ * C_;
        Bt = which ? wk2b : wk1b;
        bias = which ? bk2 : bk1;
        outp = (which ? k2b : k1b) + (size_t)b * K_ * 256;
        m0 = bx * 64; n0 = by * 64; po = 256; bias_m = false;
    } else {
        int id2 = id - 256;
        int bx = id2 & 7, by = (id2 >> 3) & 1, z = id2 >> 4;
        int b = z >> 1, which = z & 1;
        A = which ? wv2b : wv1b;
        Bt = (which ? y2b : y1b) + (size_t)b * K_ * C_;
        bias = which ? bv2 : bv1;
        outp = (which ? vt2 : vt1) + (size_t)b * C_ * K_;
        m0 = bx * 64; n0 = by * 64; po = 128; bias_m = true;
    }
    floatx4 acc[4][4] = {};
    for (int ch = 0; ch < 16; ++ch) {
        int koff = ch * 32 + (l >> 4) * 8;
        short8v a[4], wv[4];
#pragma unroll
        for (int mf = 0; mf < 4; ++mf) a[mf] = *(const short8v*)(A + (size_t)(m0 + mf*16 + (l & 15)) * 512 + koff);
#pragma unroll
        for (int nf = 0; nf < 4; ++nf) wv[nf] = *(const short8v*)(Bt + (size_t)(n0 + nf*16 + (l & 15)) * 512 + koff);
#pragma unroll
        for (int mf = 0; mf < 4; ++mf)
#pragma unroll
            for (int nf = 0; nf < 4; ++nf)
                acc[mf][nf] = __builtin_amdgcn_mfma_f32_16x16x32_bf16(a[mf], wv[nf], acc[mf][nf], 0, 0, 0);
    }
#pragma unroll
    for (int mf = 0; mf < 4; ++mf)
#pragma unroll
        for (int nf = 0; nf < 4; ++nf)
#pragma unroll
            for (int rg = 0; rg < 4; ++rg) {
                int m = m0 + mf*16 + (l >> 4)*4 + rg;
                int n = n0 + nf*16 + (l & 15);
                outp[(size_t)m * po + n] = f2bf(acc[mf][nf][rg] + (bias_m ? bias[m] : bias[n]));
            }
}

// ---------------------------------------------------------------------------
// P2: kd = k1b - k2b (bf16); P2b: ebd = bq_cat . kd_row
// ---------------------------------------------------------------------------
__global__ void kd_sub(const u16* __restrict__ k1b, const u16* __restrict__ k2b,
                       u16* kd) {
    int tid = blockIdx.x * 256 + threadIdx.x;
    kd[tid] = f2bf(bf2f(k1b[tid]) - bf2f(k2b[tid]));
}

__global__ void ebd_k(const u16* __restrict__ kd,
                      const float* __restrict__ bq1, const float* __restrict__ bq2,
                      float* ebd) {
    int tid = blockIdx.x * 256 + threadIdx.x;  // 2048
    const u16* kb = kd + (size_t)tid * 256;
    float s = 0.f;
    for (int d = 0; d < 128; ++d) s += bq1[d] * bf2f(kb[d]);
    for (int d = 0; d < 128; ++d) s += bq2[d] * bf2f(kb[128 + d]);
    ebd[tid] = s;
}

// ---------------------------------------------------------------------------
// P3: kkd1/kkd2 [b][key][512] bf16 = kd_half @ wqt^T (K=128 over d)
// ---------------------------------------------------------------------------
__global__ void gemm_gkk(const u16* __restrict__ kd,
                         const u16* __restrict__ wq1t, const u16* __restrict__ wq2t,
                         u16* kkd1, u16* kkd2) {
    int l = threadIdx.x;
    int z = blockIdx.z; int b = z >> 1; int which = z & 1;
    const u16* A = kd + (size_t)b * K_ * 256 + which * 128;
    const u16* Wt = which ? wq2t : wq1t;
    u16* outp = (which ? kkd2 : kkd1) + (size_t)b * K_ * C_;
    int m0 = blockIdx.x * 64, n0 = blockIdx.y * 64;
    floatx4 acc[4][4] = {};
    for (int ch = 0; ch < 4; ++ch) {
        int koff = ch * 32 + (l >> 4) * 8;
        short8v a[4], wv[4];
#pragma unroll
        for (int mf = 0; mf < 4; ++mf) a[mf] = *(const short8v*)(A + (size_t)(m0 + mf*16 + (l & 15)) * 256 + koff);
#pragma unroll
        for (int nf = 0; nf < 4; ++nf) wv[nf] = *(const short8v*)(Wt + (size_t)(n0 + nf*16 + (l & 15)) * 128 + koff);
#pragma unroll
        for (int mf = 0; mf < 4; ++mf)
#pragma unroll
            for (int nf = 0; nf < 4; ++nf)
                acc[mf][nf] = __builtin_amdgcn_mfma_f32_16x16x32_bf16(a[mf], wv[nf], acc[mf][nf], 0, 0, 0);
    }
#pragma unroll
    for (int mf = 0; mf < 4; ++mf)
#pragma unroll
        for (int nf = 0; nf < 4; ++nf)
#pragma unroll
            for (int rg = 0; rg < 4; ++rg) {
                int m = m0 + mf*16 + (l >> 4)*4 + rg;
                int n = n0 + nf*16 + (l & 15);
                outp[(size_t)m * C_ + n] = f2bf(acc[mf][nf][rg]);
            }
}

// ---------------------------------------------------------------------------
// E kernel: ediff = x_cat . kkd_cat (K=1024) + ebd, softmax(|.|) fused, attn out.
// grid 512, block 256 (4 waves). Tile 128 px x 128 keys.
// Pipeline: 3 rotating x register buffers (SLOADX(s+3) issued a full region
// before SWRITEX(s+3)); issue order KLDS -> compute -> SWRITEX -> SLOADX per
// region, pinned; vmcnt(16) at steady barriers drains exactly {1-region-old
// x loads, KLDS} and keeps the 16 newest x loads in flight across barriers.
// ---------------------------------------------------------------------------
__global__ __launch_bounds__(256, 2)
void e_attn(const float* __restrict__ x1, const float* __restrict__ x2,
            const u16* __restrict__ kkd1, const u16* __restrict__ kkd2,
            const float* __restrict__ ebd, u16* __restrict__ attnb) {
    __shared__ u16 xT[2][128 * 64];    // 2x16 KB  [px][ch] bf16 swizzled
    __shared__ u16 kkS[2][128 * 64];   // 2x16 KB  [key][ch] bf16 (content pre-swizzled)

    int id = blockIdx.x;
    int sw = ((id & 7) << 6) | (id >> 3);   // XCD swizzle, 512 = 8*64 bijective
    int b = sw >> 5;
    int n0 = (sw & 31) * 128;
    int t = threadIdx.x, w = t >> 6, l = t & 63;

    const float* xs[2] = { x1 + (size_t)b * C_ * N_, x2 + (size_t)b * C_ * N_ };
    const u16* kkp[2] = { kkd1 + (size_t)b * K_ * C_, kkd2 + (size_t)b * K_ * C_ };

    floatx4 ed[2][8] = {};   // wave: px rows w*32+mf*16.., all 128 keys

    float xv0_0[16], xv1_0[16], xv0_1[16], xv1_1[16], xv0_2[16], xv1_2[16];

    auto SLOADX = [&](int s, float (&v0)[16], float (&v1)[16]) {
        int h = s >> 3, c0 = (s & 7) * 64;
        const float* xp = xs[h] + (size_t)(c0 + w * 16) * N_ + n0 + 2 * l;
#pragma unroll
        for (int j = 0; j < 16; ++j) {
            float2 f = *(const float2*)(xp + (size_t)j * N_);
            v0[j] = f.x; v1[j] = f.y;
        }
    };
    // async kk stage: granule gi = i*256+t; key = gi>>3, phys granule gp = gi&7;
    // source granule = gp ^ (key&7)  =>  read at 8*(g^(key&7)) returns granule g.
    auto KLDS = [&](int s, int buf) {
        int h = s >> 3, c0 = (s & 7) * 64;
        const u16* kp = kkp[h] + c0;
#pragma unroll
        for (int i = 0; i < 4; ++i) {
            int gi = i * 256 + t;
            int key = gi >> 3, gp = gi & 7;
            gload_lds16(kp + (size_t)key * 512 + (gp ^ (key & 7)) * 8,
                        &kkS[buf][(i * 256 + w * 64) * 8]);
        }
    };
    auto SWRITEX = [&](int buf, float (&v0)[16], float (&v1)[16]) {
        short8v p00, p01, p10, p11;
#pragma unroll
        for (int j = 0; j < 8; ++j) {
            p00[j] = (short)f2bf(v0[j]);  p01[j] = (short)f2bf(v0[j + 8]);
            p10[j] = (short)f2bf(v1[j]);  p11[j] = (short)f2bf(v1[j + 8]);
        }
        u16* xb = xT[buf];
        int row0 = 2 * l, sz = l & 7;
        *(short8v*)&xb[row0 * 64 + 8 * ((w * 2) ^ sz)] = p00;
        *(short8v*)&xb[row0 * 64 + 8 * ((w * 2 + 1) ^ sz)] = p01;
        *(short8v*)&xb[(row0 + 1) * 64 + 8 * ((w * 2) ^ sz)] = p10;
        *(short8v*)&xb[(row0 + 1) * 64 + 8 * ((w * 2 + 1) ^ sz)] = p11;
    };
    auto COMPUTE = [&](int buf) {
        u16* xb = xT[buf]; u16* kb = kkS[buf];
#pragma unroll
        for (int cc = 0; cc < 2; ++cc) {
            short8v a[2];
#pragma unroll
            for (int mf = 0; mf < 2; ++mf) {
                int row = w * 32 + mf * 16 + (l & 15);
                int g = cc * 4 + (l >> 4);
                a[mf] = *(const short8v*)&xb[row * 64 + 8 * (g ^ ((row >> 1) & 7))];
            }
#pragma unroll
            for (int kf = 0; kf < 8; ++kf) {
                int key = kf * 16 + (l & 15);
                int g = cc * 4 + (l >> 4);
                short8v bb = *(const short8v*)&kb[key * 64 + 8 * (g ^ (key & 7))];
#pragma unroll
                for (int mf = 0; mf < 2; ++mf)
                    ed[mf][kf] = __builtin_amdgcn_mfma_f32_16x16x32_bf16(a[mf], bb, ed[mf][kf], 0, 0, 0);
            }
        }
    };

    // Region S: KLDS(S+1) [pinned first]; COMPUTE(S); SWRITEX(S+1, xR[(S+1)%3]);
    //           SLOADX(S+3, xR[S%3]); barrier vmcnt(VMC).
#define REGION(S, XW0, XW1, XL0, XL1, DO_W, DO_L, VMC) do { \
        if ((S) + 1 <= 15) KLDS((S) + 1, ((S) + 1) & 1); \
        __builtin_amdgcn_sched_barrier(0); \
        COMPUTE((S) & 1); \
        if (DO_W) SWRITEX(((S) + 1) & 1, XW0, XW1); \
        if (DO_L) SLOADX((S) + 3, XL0, XL1); \
        BARRIER_VM(VMC); \
    } while (0)

    // ---- prologue: loads for steps 0,1,2; kk for step 0; stage x step 0
    SLOADX(0, xv0_0, xv1_0);
    KLDS(0, 0);
    __builtin_amdgcn_sched_barrier(0);
    SLOADX(1, xv0_1, xv1_1);
    SLOADX(2, xv0_2, xv1_2);
    SWRITEX(0, xv0_0, xv1_0);          // compiler drains SLOADX(0) here
    BARRIER_VM(32);                     // drains KLDS(0); keeps SLOADX(1),(2)

    // ---- steady state: steps 0..11 (unroll by 3 to fix buffer rotation)
#pragma unroll
    for (int k3 = 0; k3 < 4; ++k3) {
        int s0 = k3 * 3;
        REGION(s0 + 0, xv0_1, xv1_1, xv0_0, xv1_0, 1, 1, 16);
        REGION(s0 + 1, xv0_2, xv1_2, xv0_1, xv1_1, 1, 1, 16);
        REGION(s0 + 2, xv0_0, xv1_0, xv0_2, xv1_2, 1, 1, 16);
    }
    // ---- tail: steps 12..15
    REGION(12, xv0_1, xv1_1, xv0_0, xv1_0, 1, 1, 16);   // SLOADX(15) -> buf0
    REGION(13, xv0_2, xv1_2, xv0_0, xv1_0, 1, 0, 0);    // no more loads
    REGION(14, xv0_0, xv1_0, xv0_0, xv1_0, 1, 0, 0);    // SWRITEX(15) from buf0
    COMPUTE(15 & 1);                                     // last step, no barrier
#undef REGION

    // ---- fused softmax over 128 keys of |ediff + ebd| (in-register)
    float ebv[8];
#pragma unroll
    for (int kf = 0; kf < 8; ++kf) ebv[kf] = ebd[b * 128 + kf * 16 + (l & 15)];
#pragma unroll
    for (int mf = 0; mf < 2; ++mf)
#pragma unroll
        for (int kf = 0; kf < 8; ++kf)
#pragma unroll
            for (int rg = 0; rg < 4; ++rg)
                ed[mf][kf][rg] = fabsf(ed[mf][kf][rg] + ebv[kf]);

    float mx[2][4], sm[2][4];
#pragma unroll
    for (int mf = 0; mf < 2; ++mf)
#pragma unroll
        for (int rg = 0; rg < 4; ++rg) {
            float m = fmaxf(ed[mf][0][rg], ed[mf][1][rg]);
            m = fmaxf(m, fmaxf(ed[mf][2][rg], ed[mf][3][rg]));
            m = fmaxf(m, fmaxf(ed[mf][4][rg], ed[mf][5][rg]));
            m = fmaxf(m, fmaxf(ed[mf][6][rg], ed[mf][7][rg]));
            mx[mf][rg] = m;
        }
#pragma unroll
    for (int st = 1; st < 16; st <<= 1)
#pragma unroll
        for (int mf = 0; mf < 2; ++mf)
#pragma unroll
            for (int rg = 0; rg < 4; ++rg)
                mx[mf][rg] = fmaxf(mx[mf][rg], __shfl_xor(mx[mf][rg], st));
#pragma unroll
    for (int mf = 0; mf < 2; ++mf)
#pragma unroll
        for (int rg = 0; rg < 4; ++rg) sm[mf][rg] = 0.f;
#pragma unroll
    for (int mf = 0; mf < 2; ++mf)
#pragma unroll
        for (int kf = 0; kf < 8; ++kf)
#pragma unroll
            for (int rg = 0; rg < 4; ++rg) {
                float e = __expf(ed[mf][kf][rg] - mx[mf][rg]);
                ed[mf][kf][rg] = e;
                sm[mf][rg] += e;
            }
#pragma unroll
    for (int st = 1; st < 16; st <<= 1)
#pragma unroll
        for (int mf = 0; mf < 2; ++mf)
#pragma unroll
            for (int rg = 0; rg < 4; ++rg)
                sm[mf][rg] += __shfl_xor(sm[mf][rg], st);
#pragma unroll
    for (int mf = 0; mf < 2; ++mf)
#pragma unroll
        for (int rg = 0; rg < 4; ++rg) sm[mf][rg] = 1.0f / sm[mf][rg];

    // ---- write attn bf16 [b][px][128k]
    u16* ap = attnb + ((size_t)(b * N_ + n0)) * 128;
#pragma unroll
    for (int mf = 0; mf < 2; ++mf)
#pragma unroll
        for (int rg = 0; rg < 4; ++rg) {
            int row = w * 32 + mf * 16 + (l >> 4) * 4 + rg;
#pragma unroll
            for (int kf = 0; kf < 8; ++kf) {
                int col = kf * 16 + (l & 15);
                ap[(size_t)row * 128 + col] = f2bf(ed[mf][kf][rg] * sm[mf][rg]);
            }
        }
}

// ---------------------------------------------------------------------------
// PV kernel: O[c][n] = vt[c][k].attn[n][k]; out = sc*O + x. K=128, no K-loop.
// grid 4096, block 256 (4 waves), tile 128c x 128px. attn staged async via
// global_load_lds (pre-swizzled source); vf/rs loads pre-barrier.  [R9 VERBATIM]
// ---------------------------------------------------------------------------
__global__ __launch_bounds__(256, 2)
void pv_attn(const float* __restrict__ x1, const float* __restrict__ x2,
             const u16* __restrict__ vt1, const u16* __restrict__ vt2,
             const u16* __restrict__ attnb, const float* __restrict__ scale_p,
             float* __restrict__ out1, float* __restrict__ out2) {
    __shared__ u16 As[128 * 128];   // 32 KB, [px][k] bf16 (content pre-swizzled)

    int id = blockIdx.x;
    int sw = ((id & 7) << 9) | (id >> 3);   // XCD swizzle, 4096 = 8*512 bijective
    int b = sw >> 8;
    int ct = (sw >> 5) & 7;
    int pt = sw & 31;
    int n0 = pt * 128;
    int cb = ct * 128;
    int oi = cb >> 9;          // 0: out1/vt1/x1, 1: out2/vt2/x2
    int cbl = cb & 511;
    int t = threadIdx.x, w = t >> 6, l = t & 63;

    const float sc = scale_p[0];
    const u16* vt = (oi ? vt2 : vt1) + (size_t)b * C_ * K_;
    const float* xr = (oi ? x2 : x1) + (size_t)b * C_ * N_;
    float* op = (oi ? out2 : out1) + (size_t)b * C_ * N_;

    // async stage attn tile: granule gi = p*256+t; px = gi>>4, gp = gi&15;
    // source granule = gp ^ (px&15)  =>  read at 8*(g^(px&15)) returns granule g.
    const u16* ap = attnb + ((size_t)(b * N_ + n0)) * 128;
#pragma unroll
    for (int p = 0; p < 8; ++p) {
        int gi = p * 256 + t;
        int px = gi >> 4, gp = gi & 15;
        gload_lds16(ap + (size_t)px * 128 + (gp ^ (px & 15)) * 8,
                    &As[(p * 256 + w * 64) * 8]);
    }

    // vt A-frags (L2) + residual loads issued before the barrier (overlap staging)
    short8v vf[2][4];
#pragma unroll
    for (int mf = 0; mf < 2; ++mf)
#pragma unroll
        for (int kc = 0; kc < 4; ++kc)
            vf[mf][kc] = *(const short8v*)(vt + (size_t)(cbl + w * 32 + mf * 16 + (l & 15)) * K_ + kc * 32 + (l >> 4) * 8);

    float rs[2][4][8];
#pragma unroll
    for (int mf = 0; mf < 2; ++mf)
#pragma unroll
        for (int rg = 0; rg < 4; ++rg) {
            const float* rp = xr + (size_t)(cbl + w * 32 + mf * 16 + (l >> 4) * 4 + rg) * N_ + n0 + (l & 15);
#pragma unroll
            for (int nf = 0; nf < 8; ++nf)
                rs[mf][rg][nf] = rp[nf * 16];
        }
    __syncthreads();   // the only barrier (drains gload_lds)

    floatx4 o[2][8] = {};
#pragma unroll
    for (int kc = 0; kc < 4; ++kc) {
#pragma unroll
        for (int nf = 0; nf < 8; ++nf) {
            int row = nf * 16 + (l & 15);
            int g = kc * 4 + (l >> 4);
            short8v bb = *(const short8v*)&As[row * 128 + 8 * (g ^ (row & 15))];
#pragma unroll
            for (int mf = 0; mf < 2; ++mf)
                o[mf][nf] = __builtin_amdgcn_mfma_f32_16x16x32_bf16(vf[mf][kc], bb, o[mf][nf], 0, 0, 0);
        }
    }

#pragma unroll
    for (int mf = 0; mf < 2; ++mf)
#pragma unroll
        for (int rg = 0; rg < 4; ++rg) {
            float* wp = op + (size_t)(cbl + w * 32 + mf * 16 + (l >> 4) * 4 + rg) * N_ + n0 + (l & 15);
#pragma unroll
            for (int nf = 0; nf < 8; ++nf)
                wp[nf * 16] = sc * o[mf][nf][rg] + rs[mf][rg][nf];
        }
}

// ---------------------------------------------------------------------------
extern "C" void kernel_launch(void* const* d_in, const int* in_sizes, int n_in,
                              void* d_out, int out_size, void* d_ws, size_t ws_size,
                              hipStream_t stream) {
    const float* x1 = (const float*)d_in[0];
    const float* y1 = (const float*)d_in[1];
    const float* x2 = (const float*)d_in[2];
    const float* y2 = (const float*)d_in[3];
    const float* wq1 = (const float*)d_in[4];
    const float* bq1 = (const float*)d_in[5];
    const float* wq2 = (const float*)d_in[6];
    const float* bq2 = (const float*)d_in[7];
    const float* wk1 = (const float*)d_in[8];
    const float* bk1 = (const float*)d_in[9];
    const float* wk2 = (const float*)d_in[10];
    const float* bk2 = (const float*)d_in[11];
    const float* wv1 = (const float*)d_in[12];
    const float* bv1 = (const float*)d_in[13];
    const float* wv2 = (const float*)d_in[14];
    const float* bv2 = (const float*)d_in[15];
    const float* scale = (const float*)d_in[16];

    char* ws = (char*)d_ws;
    u16* y1b  = (u16*)(ws + 0);
    u16* y2b  = (u16*)(ws + 2097152);
    u16* wk1b = (u16*)(ws + 4194304);
    u16* wk2b = (u16*)(ws + 4456448);
    u16* wv1b = (u16*)(ws + 4718592);
    u16* wv2b = (u16*)(ws + 5242880);
    u16* wq1t = (u16*)(ws + 5767168);
    u16* wq2t = (u16*)(ws + 5898240);
    u16* k1b  = (u16*)(ws + 6029312);
    u16* k2b  = (u16*)(ws + 7077888);
    u16* kd   = (u16*)(ws + 8126464);
    u16* kkd1 = (u16*)(ws + 9175040);
    u16* kkd2 = (u16*)(ws + 11272192);
    u16* vt1  = (u16*)(ws + 13369344);
    u16* vt2  = (u16*)(ws + 15466496);
    float* ebd = (float*)(ws + 17563648);
    u16* attnb = (u16*)(ws + 17571840);   // 16 MB

    float* out1 = (float*)d_out;
    float* out2 = out1 + (size_t)B_ * C_ * N_;

    hipLaunchKernelGGL(conv_all, dim3(11776), dim3(256), 0, stream,
                       y1, y2, wk1, wk2, wv1, wv2, wq1, wq2,
                       y1b, y2b, wk1b, wk2b, wv1b, wv2b, wq1t, wq2t);
    hipLaunchKernelGGL(gemm_gkgv, dim3(768), dim3(64), 0, stream,
                       y1b, y2b, wk1b, wk2b, wv1b, wv2b, bk1, bk2, bv1, bv2,
                       k1b, k2b, vt1, vt2);
    hipLaunchKernelGGL(kd_sub, dim3(2048), dim3(256), 0, stream, k1b, k2b, kd);
    hipLaunchKernelGGL(ebd_k, dim3(8), dim3(256), 0, stream, kd, bq1, bq2, ebd);
    hipLaunchKernelGGL(gemm_gkk, dim3(2, 8, 32), dim3(64), 0, stream,
                       kd, wq1t, wq2t, kkd1, kkd2);
    hipLaunchKernelGGL(e_attn, dim3(512), dim3(256), 0, stream,
                       x1, x2, kkd1, kkd2, ebd, attnb);
    hipLaunchKernelGGL(pv_attn, dim3(4096), dim3(256), 0, stream,
                       x1, x2, vt1, vt2, attnb, scale, out1, out2);
}

// Round 14
// 215.547 us; speedup vs baseline: 1.0794x; 1.0794x over previous
//
#include <hip/hip_runtime.h>

typedef unsigned short u16;
typedef __attribute__((ext_vector_type(8))) short short8v;
typedef __attribute__((ext_vector_type(4))) float floatx4;

#define B_ 16
#define C_ 512
#define N_ 4096
#define K_ 128   // keys

__device__ __forceinline__ float bf2f(u16 u) {
    unsigned int x = ((unsigned int)u) << 16;
    return __builtin_bit_cast(float, x);
}
__device__ __forceinline__ u16 f2bf(float f) {
    unsigned int u = __builtin_bit_cast(unsigned int, f);
    u = u + 0x7FFFu + ((u >> 16) & 1u);
    return (u16)(u >> 16);
}
// async global(16B) -> LDS, wave-uniform dest base + lane*16
__device__ __forceinline__ void gload_lds16(const u16* g, u16* l) {
    __builtin_amdgcn_global_load_lds(
        (const __attribute__((address_space(1))) void*)g,
        (__attribute__((address_space(3))) void*)l, 16, 0, 0);
}

// counted-vmcnt barrier (R12-proven): 8 newest x loads stay in flight.
#define BARRIER_V8 do { \
    asm volatile("s_waitcnt vmcnt(8) lgkmcnt(0)" ::: "memory"); \
    __builtin_amdgcn_s_barrier(); \
    __builtin_amdgcn_sched_barrier(0); \
} while (0)
#define BARRIER_V0 do { \
    asm volatile("s_waitcnt vmcnt(0) lgkmcnt(0)" ::: "memory"); \
    __builtin_amdgcn_s_barrier(); \
    __builtin_amdgcn_sched_barrier(0); \
} while (0)

// ---------------------------------------------------------------------------
// P0: fp32 -> bf16 converts (y1,y2,wk1,wk2,wv1,wv2) + wq transpose, one launch
// ---------------------------------------------------------------------------
__global__ void conv_all(const float* __restrict__ y1, const float* __restrict__ y2,
                         const float* __restrict__ wk1, const float* __restrict__ wk2,
                         const float* __restrict__ wv1, const float* __restrict__ wv2,
                         const float* __restrict__ wq1, const float* __restrict__ wq2,
                         u16* y1b, u16* y2b, u16* wk1b, u16* wk2b, u16* wv1b, u16* wv2b,
                         u16* wq1t, u16* wq2t) {
    int tid = blockIdx.x * 256 + threadIdx.x;
    const int SY = B_ * K_ * C_;        // 1048576
    const int SWK = 256 * 512;          // 131072
    const int SWV = 512 * 512;          // 262144
    const int SQ = 128 * 512;           // 65536
    int base = 2*SY + 2*SWK + 2*SWV;
    if (tid < base) {
        const float* src; u16* dst; int off;
        if (tid < SY)                 { src = y1;  dst = y1b;  off = tid; }
        else if (tid < 2*SY)          { src = y2;  dst = y2b;  off = tid - SY; }
        else if (tid < 2*SY+SWK)      { src = wk1; dst = wk1b; off = tid - 2*SY; }
        else if (tid < 2*SY+2*SWK)    { src = wk2; dst = wk2b; off = tid - 2*SY - SWK; }
        else if (tid < 2*SY+2*SWK+SWV){ src = wv1; dst = wv1b; off = tid - 2*SY - 2*SWK; }
        else                          { src = wv2; dst = wv2b; off = tid - 2*SY - 2*SWK - SWV; }
        dst[off] = f2bf(src[off]);
    } else {
        int e = tid - base;           // 0 .. 2*SQ-1
        const float* s = (e >= SQ) ? wq2 : wq1;
        u16* d = (e >= SQ) ? wq2t : wq1t;
        e &= (SQ - 1);
        int dd = e >> 9;              // 0..127
        int c = e & 511;              // coalesced read over c
        d[c * 128 + dd] = f2bf(s[dd * 512 + c]);
    }
}

// ---------------------------------------------------------------------------
// P1: k1b/k2b [b][key][256] = y @ wk^T + bk  AND  vt1/vt2 [b][c][128] = (y@wv^T+bv)^T
// ---------------------------------------------------------------------------
__global__ void gemm_gkgv(const u16* __restrict__ y1b, const u16* __restrict__ y2b,
                          const u16* __restrict__ wk1b, const u16* __restrict__ wk2b,
                          const u16* __restrict__ wv1b, const u16* __restrict__ wv2b,
                          const float* __restrict__ bk1, const float* __restrict__ bk2,
                          const float* __restrict__ bv1, const float* __restrict__ bv2,
                          u16* k1b, u16* k2b, u16* vt1, u16* vt2) {
    int l = threadIdx.x;
    int id = blockIdx.x;
    const u16 *A, *Bt; const float* bias; u16* outp;
    int m0, n0, po; bool bias_m;
    if (id < 256) {
        int bx = id & 1, by = (id >> 1) & 3, z = id >> 3;
        int b = z >> 1, which = z & 1;
        A = (which ? y2b : y1b) + (size_t)b * K_ * C_;
        Bt = which ? wk2b : wk1b;
        bias = which ? bk2 : bk1;
        outp = (which ? k2b : k1b) + (size_t)b * K_ * 256;
        m0 = bx * 64; n0 = by * 64; po = 256; bias_m = false;
    } else {
        int id2 = id - 256;
        int bx = id2 & 7, by = (id2 >> 3) & 1, z = id2 >> 4;
        int b = z >> 1, which = z & 1;
        A = which ? wv2b : wv1b;
        Bt = (which ? y2b : y1b) + (size_t)b * K_ * C_;
        bias = which ? bv2 : bv1;
        outp = (which ? vt2 : vt1) + (size_t)b * C_ * K_;
        m0 = bx * 64; n0 = by * 64; po = 128; bias_m = true;
    }
    floatx4 acc[4][4] = {};
    for (int ch = 0; ch < 16; ++ch) {
        int koff = ch * 32 + (l >> 4) * 8;
        short8v a[4], wv[4];
#pragma unroll
        for (int mf = 0; mf < 4; ++mf) a[mf] = *(const short8v*)(A + (size_t)(m0 + mf*16 + (l & 15)) * 512 + koff);
#pragma unroll
        for (int nf = 0; nf < 4; ++nf) wv[nf] = *(const short8v*)(Bt + (size_t)(n0 + nf*16 + (l & 15)) * 512 + koff);
#pragma unroll
        for (int mf = 0; mf < 4; ++mf)
#pragma unroll
            for (int nf = 0; nf < 4; ++nf)
                acc[mf][nf] = __builtin_amdgcn_mfma_f32_16x16x32_bf16(a[mf], wv[nf], acc[mf][nf], 0, 0, 0);
    }
#pragma unroll
    for (int mf = 0; mf < 4; ++mf)
#pragma unroll
        for (int nf = 0; nf < 4; ++nf)
#pragma unroll
            for (int rg = 0; rg < 4; ++rg) {
                int m = m0 + mf*16 + (l >> 4)*4 + rg;
                int n = n0 + nf*16 + (l & 15);
                outp[(size_t)m * po + n] = f2bf(acc[mf][nf][rg] + (bias_m ? bias[m] : bias[n]));
            }
}

// ---------------------------------------------------------------------------
// P2: kd = k1b - k2b (bf16); P2b: ebd = bq_cat . kd_row
// ---------------------------------------------------------------------------
__global__ void kd_sub(const u16* __restrict__ k1b, const u16* __restrict__ k2b,
                       u16* kd) {
    int tid = blockIdx.x * 256 + threadIdx.x;
    kd[tid] = f2bf(bf2f(k1b[tid]) - bf2f(k2b[tid]));
}

__global__ void ebd_k(const u16* __restrict__ kd,
                      const float* __restrict__ bq1, const float* __restrict__ bq2,
                      float* ebd) {
    int tid = blockIdx.x * 256 + threadIdx.x;  // 2048
    const u16* kb = kd + (size_t)tid * 256;
    float s = 0.f;
    for (int d = 0; d < 128; ++d) s += bq1[d] * bf2f(kb[d]);
    for (int d = 0; d < 128; ++d) s += bq2[d] * bf2f(kb[128 + d]);
    ebd[tid] = s;
}

// ---------------------------------------------------------------------------
// P3: kkd1/kkd2 [b][key][512] bf16 = kd_half @ wqt^T (K=128 over d)
// ---------------------------------------------------------------------------
__global__ void gemm_gkk(const u16* __restrict__ kd,
                         const u16* __restrict__ wq1t, const u16* __restrict__ wq2t,
                         u16* kkd1, u16* kkd2) {
    int l = threadIdx.x;
    int z = blockIdx.z; int b = z >> 1; int which = z & 1;
    const u16* A = kd + (size_t)b * K_ * 256 + which * 128;
    const u16* Wt = which ? wq2t : wq1t;
    u16* outp = (which ? kkd2 : kkd1) + (size_t)b * K_ * C_;
    int m0 = blockIdx.x * 64, n0 = blockIdx.y * 64;
    floatx4 acc[4][4] = {};
    for (int ch = 0; ch < 4; ++ch) {
        int koff = ch * 32 + (l >> 4) * 8;
        short8v a[4], wv[4];
#pragma unroll
        for (int mf = 0; mf < 4; ++mf) a[mf] = *(const short8v*)(A + (size_t)(m0 + mf*16 + (l & 15)) * 256 + koff);
#pragma unroll
        for (int nf = 0; nf < 4; ++nf) wv[nf] = *(const short8v*)(Wt + (size_t)(n0 + nf*16 + (l & 15)) * 128 + koff);
#pragma unroll
        for (int mf = 0; mf < 4; ++mf)
#pragma unroll
            for (int nf = 0; nf < 4; ++nf)
                acc[mf][nf] = __builtin_amdgcn_mfma_f32_16x16x32_bf16(a[mf], wv[nf], acc[mf][nf], 0, 0, 0);
    }
#pragma unroll
    for (int mf = 0; mf < 4; ++mf)
#pragma unroll
        for (int nf = 0; nf < 4; ++nf)
#pragma unroll
            for (int rg = 0; rg < 4; ++rg) {
                int m = m0 + mf*16 + (l >> 4)*4 + rg;
                int n = n0 + nf*16 + (l & 15);
                outp[(size_t)m * C_ + n] = f2bf(acc[mf][nf][rg]);
            }
}

// ---------------------------------------------------------------------------
// Fused kernel: E (R12-verbatim counted-vmcnt loop) + in-reg softmax + attn
// published to kkS-aliased LDS + PV with depth-1 REGISTER prefetch of vf AND rs
// (the R8/R10 failure was streaming rs in the epilogue — fixed here).
// grid 512 (16b x 32 px-tiles), block 256 (4 waves), LDS 64 KB, 2 blocks/CU.
// ---------------------------------------------------------------------------
__global__ __launch_bounds__(256, 2)
void fused_attn(const float* __restrict__ x1, const float* __restrict__ x2,
                const u16* __restrict__ kkd1, const u16* __restrict__ kkd2,
                const u16* __restrict__ vt1, const u16* __restrict__ vt2,
                const float* __restrict__ ebd, const float* __restrict__ scale_p,
                float* __restrict__ out1, float* __restrict__ out2) {
    __shared__ u16 smem[32768];                    // 64 KB
    u16* xT[2]  = { smem,         smem + 8192 };   // 2x16 KB [px][ch] swizzled
    u16* kkS[2] = { smem + 16384, smem + 24576 };  // 2x16 KB [key][ch] (pre-swz src)
    u16* attn_s = smem + 16384;                    // 32 KB [px][128k], aliases kkS

    int id = blockIdx.x;
    int sw = ((id & 7) << 6) | (id >> 3);   // XCD swizzle, 512 = 8*64 bijective
    int b = sw >> 5;
    int n0 = (sw & 31) * 128;
    int t = threadIdx.x, w = t >> 6, l = t & 63;

    const float* xs[2] = { x1 + (size_t)b * C_ * N_, x2 + (size_t)b * C_ * N_ };
    const u16* kkp[2] = { kkd1 + (size_t)b * K_ * C_, kkd2 + (size_t)b * K_ * C_ };

    floatx4 ed[2][8] = {};   // wave: px rows w*32+mf*16.., all 128 keys

    float xA0[16], xA1[16], xB0[16], xB1[16];

    auto SLOADX = [&](int s, float (&v0)[16], float (&v1)[16]) {
        int h = s >> 3, c0 = (s & 7) * 64;
        const float* xp = xs[h] + (size_t)(c0 + w * 16) * N_ + n0 + 2 * l;
#pragma unroll
        for (int j = 0; j < 16; ++j) {
            float2 f = *(const float2*)(xp + (size_t)j * N_);
            v0[j] = f.x; v1[j] = f.y;
        }
    };
    // async kk stage: granule gi = i*256+t; key = gi>>3, phys granule gp = gi&7;
    // source granule = gp ^ (key&7)  =>  read at 8*(g^(key&7)) returns granule g.
    auto KLDS = [&](int s, int buf) {
        int h = s >> 3, c0 = (s & 7) * 64;
        const u16* kp = kkp[h] + c0;
#pragma unroll
        for (int i = 0; i < 4; ++i) {
            int gi = i * 256 + t;
            int key = gi >> 3, gp = gi & 7;
            gload_lds16(kp + (size_t)key * 512 + (gp ^ (key & 7)) * 8,
                        &kkS[buf][(i * 256 + w * 64) * 8]);
        }
    };
    auto SWRITEX = [&](int buf, float (&v0)[16], float (&v1)[16]) {
        short8v p00, p01, p10, p11;
#pragma unroll
        for (int j = 0; j < 8; ++j) {
            p00[j] = (short)f2bf(v0[j]);  p01[j] = (short)f2bf(v0[j + 8]);
            p10[j] = (short)f2bf(v1[j]);  p11[j] = (short)f2bf(v1[j + 8]);
        }
        u16* xb = xT[buf];
        int row0 = 2 * l, sz = l & 7;
        *(short8v*)&xb[row0 * 64 + 8 * ((w * 2) ^ sz)] = p00;
        *(short8v*)&xb[row0 * 64 + 8 * ((w * 2 + 1) ^ sz)] = p01;
        *(short8v*)&xb[(row0 + 1) * 64 + 8 * ((w * 2) ^ sz)] = p10;
        *(short8v*)&xb[(row0 + 1) * 64 + 8 * ((w * 2 + 1) ^ sz)] = p11;
    };
    auto COMPUTE = [&](int buf) {
        u16* xb = xT[buf]; u16* kb = kkS[buf];
#pragma unroll
        for (int cc = 0; cc < 2; ++cc) {
            short8v a[2];
#pragma unroll
            for (int mf = 0; mf < 2; ++mf) {
                int row = w * 32 + mf * 16 + (l & 15);
                int g = cc * 4 + (l >> 4);
                a[mf] = *(const short8v*)&xb[row * 64 + 8 * (g ^ ((row >> 1) & 7))];
            }
#pragma unroll
            for (int kf = 0; kf < 8; ++kf) {
                int key = kf * 16 + (l & 15);
                int g = cc * 4 + (l >> 4);
                short8v bb = *(const short8v*)&kb[key * 64 + 8 * (g ^ (key & 7))];
#pragma unroll
                for (int mf = 0; mf < 2; ++mf)
                    ed[mf][kf] = __builtin_amdgcn_mfma_f32_16x16x32_bf16(a[mf], bb, ed[mf][kf], 0, 0, 0);
            }
        }
    };

    // ---- E phase (R12-verbatim): 16 steps of 64 ch, counted-vmcnt barriers
    SLOADX(0, xA0, xA1); KLDS(0, 0);
    SWRITEX(0, xA0, xA1);
    SLOADX(1, xB0, xB1); KLDS(1, 1);
#pragma unroll
    for (int rr = 0; rr < 8; ++rr) {
        int sA = 2 * rr, sB = 2 * rr + 1;
        BARRIER_V8;
        if (rr > 0) KLDS(sB, 1);
        COMPUTE(0);
        SWRITEX(1, xB0, xB1);
        if (sA + 2 <= 15) SLOADX(sA + 2, xA0, xA1);
        if (rr == 7) { BARRIER_V0; }
        else         { BARRIER_V8; }
        if (sA + 2 <= 15) KLDS(sA + 2, 0);
        COMPUTE(1);
        if (sB + 1 <= 15) SWRITEX(0, xA0, xA1);
        if (sB + 2 <= 15) SLOADX(sB + 2, xB0, xB1);
    }

    // ---- fused softmax over 128 keys of |ediff + ebd| (in-register)
    float ebv[8];
#pragma unroll
    for (int kf = 0; kf < 8; ++kf) ebv[kf] = ebd[b * 128 + kf * 16 + (l & 15)];
#pragma unroll
    for (int mf = 0; mf < 2; ++mf)
#pragma unroll
        for (int kf = 0; kf < 8; ++kf)
#pragma unroll
            for (int rg = 0; rg < 4; ++rg)
                ed[mf][kf][rg] = fabsf(ed[mf][kf][rg] + ebv[kf]);

    float mx[2][4], sm[2][4];
#pragma unroll
    for (int mf = 0; mf < 2; ++mf)
#pragma unroll
        for (int rg = 0; rg < 4; ++rg) {
            float m = fmaxf(ed[mf][0][rg], ed[mf][1][rg]);
            m = fmaxf(m, fmaxf(ed[mf][2][rg], ed[mf][3][rg]));
            m = fmaxf(m, fmaxf(ed[mf][4][rg], ed[mf][5][rg]));
            m = fmaxf(m, fmaxf(ed[mf][6][rg], ed[mf][7][rg]));
            mx[mf][rg] = m;
        }
#pragma unroll
    for (int st = 1; st < 16; st <<= 1)
#pragma unroll
        for (int mf = 0; mf < 2; ++mf)
#pragma unroll
            for (int rg = 0; rg < 4; ++rg)
                mx[mf][rg] = fmaxf(mx[mf][rg], __shfl_xor(mx[mf][rg], st));
#pragma unroll
    for (int mf = 0; mf < 2; ++mf)
#pragma unroll
        for (int rg = 0; rg < 4; ++rg) sm[mf][rg] = 0.f;
#pragma unroll
    for (int mf = 0; mf < 2; ++mf)
#pragma unroll
        for (int kf = 0; kf < 8; ++kf)
#pragma unroll
            for (int rg = 0; rg < 4; ++rg) {
                float e = __expf(ed[mf][kf][rg] - mx[mf][rg]);
                ed[mf][kf][rg] = e;
                sm[mf][rg] += e;
            }
#pragma unroll
    for (int st = 1; st < 16; st <<= 1)
#pragma unroll
        for (int mf = 0; mf < 2; ++mf)
#pragma unroll
            for (int rg = 0; rg < 4; ++rg)
                sm[mf][rg] += __shfl_xor(sm[mf][rg], st);
#pragma unroll
    for (int mf = 0; mf < 2; ++mf)
#pragma unroll
        for (int rg = 0; rg < 4; ++rg) sm[mf][rg] = 1.0f / sm[mf][rg];

    // ---- publish attn into LDS (kkS region), [px][k] swizzled 16 gran/row
    __syncthreads();                   // all waves done reading kkS
#pragma unroll
    for (int mf = 0; mf < 2; ++mf)
#pragma unroll
        for (int rg = 0; rg < 4; ++rg) {
            int row = w * 32 + mf * 16 + (l >> 4) * 4 + rg;
#pragma unroll
            for (int kf = 0; kf < 8; ++kf) {
                int col = kf * 16 + (l & 15);
                attn_s[row * 128 + 8 * ((col >> 3) ^ (row & 15)) + (col & 7)] =
                    f2bf(ed[mf][kf][rg] * sm[mf][rg]);
            }
        }
    __syncthreads();

    // ---- PV: 16 steps (2 outputs x 8 chunks of 64 c); wave owns 16 c-rows/step.
    // vf AND rs register-prefetched depth-1 (no dependent loads in epilogue).
    const float sc = scale_p[0];
    const u16* vts[2] = { vt1 + (size_t)b * C_ * K_, vt2 + (size_t)b * C_ * K_ };
    float* outs[2] = { out1 + (size_t)b * C_ * N_, out2 + (size_t)b * C_ * N_ };

    short8v vfA[4], vfB[4];
    float rsA[4][8], rsB[4][8];
    auto LOADPV = [&](int s, short8v (&vf)[4], float (&rs)[4][8]) {
        int oi = s >> 3, cc = s & 7;
        const u16* vp = vts[oi] + (size_t)(cc * 64 + w * 16 + (l & 15)) * K_ + (l >> 4) * 8;
#pragma unroll
        for (int kc = 0; kc < 4; ++kc) vf[kc] = *(const short8v*)(vp + kc * 32);
        const float* rp = xs[oi] + (size_t)(cc * 64 + w * 16 + (l >> 4) * 4) * N_ + n0 + (l & 15);
#pragma unroll
        for (int rg = 0; rg < 4; ++rg)
#pragma unroll
            for (int nf = 0; nf < 8; ++nf)
                rs[rg][nf] = rp[(size_t)rg * N_ + nf * 16];
    };
    auto COMPPV = [&](int s, short8v (&vf)[4], float (&rs)[4][8]) {
        floatx4 o[8] = {};
#pragma unroll
        for (int kc = 0; kc < 4; ++kc) {
#pragma unroll
            for (int nf = 0; nf < 8; ++nf) {
                int row = nf * 16 + (l & 15);
                int g = kc * 4 + (l >> 4);
                short8v bb = *(const short8v*)&attn_s[row * 128 + 8 * (g ^ (row & 15))];
                o[nf] = __builtin_amdgcn_mfma_f32_16x16x32_bf16(vf[kc], bb, o[nf], 0, 0, 0);
            }
        }
        int oi = s >> 3, cc = s & 7;
        float* op = outs[oi];
        int cr = cc * 64 + w * 16 + (l >> 4) * 4;
#pragma unroll
        for (int rg = 0; rg < 4; ++rg) {
            size_t rowoff = (size_t)(cr + rg) * N_ + n0 + (l & 15);
#pragma unroll
            for (int nf = 0; nf < 8; ++nf)
                op[rowoff + nf * 16] = sc * o[nf][rg] + rs[rg][nf];
        }
    };

    LOADPV(0, vfA, rsA);
    LOADPV(1, vfB, rsB);
#pragma unroll
    for (int ss = 0; ss < 8; ++ss) {
        COMPPV(2 * ss, vfA, rsA);
        if (2 * ss + 2 < 16) LOADPV(2 * ss + 2, vfA, rsA);
        COMPPV(2 * ss + 1, vfB, rsB);
        if (2 * ss + 3 < 16) LOADPV(2 * ss + 3, vfB, rsB);
    }
}

// ---------------------------------------------------------------------------
extern "C" void kernel_launch(void* const* d_in, const int* in_sizes, int n_in,
                              void* d_out, int out_size, void* d_ws, size_t ws_size,
                              hipStream_t stream) {
    const float* x1 = (const float*)d_in[0];
    const float* y1 = (const float*)d_in[1];
    const float* x2 = (const float*)d_in[2];
    const float* y2 = (const float*)d_in[3];
    const float* wq1 = (const float*)d_in[4];
    const float* bq1 = (const float*)d_in[5];
    const float* wq2 = (const float*)d_in[6];
    const float* bq2 = (const float*)d_in[7];
    const float* wk1 = (const float*)d_in[8];
    const float* bk1 = (const float*)d_in[9];
    const float* wk2 = (const float*)d_in[10];
    const float* bk2 = (const float*)d_in[11];
    const float* wv1 = (const float*)d_in[12];
    const float* bv1 = (const float*)d_in[13];
    const float* wv2 = (const float*)d_in[14];
    const float* bv2 = (const float*)d_in[15];
    const float* scale = (const float*)d_in[16];

    char* ws = (char*)d_ws;
    u16* y1b  = (u16*)(ws + 0);
    u16* y2b  = (u16*)(ws + 2097152);
    u16* wk1b = (u16*)(ws + 4194304);
    u16* wk2b = (u16*)(ws + 4456448);
    u16* wv1b = (u16*)(ws + 4718592);
    u16* wv2b = (u16*)(ws + 5242880);
    u16* wq1t = (u16*)(ws + 5767168);
    u16* wq2t = (u16*)(ws + 5898240);
    u16* k1b  = (u16*)(ws + 6029312);
    u16* k2b  = (u16*)(ws + 7077888);
    u16* kd   = (u16*)(ws + 8126464);
    u16* kkd1 = (u16*)(ws + 9175040);
    u16* kkd2 = (u16*)(ws + 11272192);
    u16* vt1  = (u16*)(ws + 13369344);
    u16* vt2  = (u16*)(ws + 15466496);
    float* ebd = (float*)(ws + 17563648);

    float* out1 = (float*)d_out;
    float* out2 = out1 + (size_t)B_ * C_ * N_;

    hipLaunchKernelGGL(conv_all, dim3(11776), dim3(256), 0, stream,
                       y1, y2, wk1, wk2, wv1, wv2, wq1, wq2,
                       y1b, y2b, wk1b, wk2b, wv1b, wv2b, wq1t, wq2t);
    hipLaunchKernelGGL(gemm_gkgv, dim3(768), dim3(64), 0, stream,
                       y1b, y2b, wk1b, wk2b, wv1b, wv2b, bk1, bk2, bv1, bv2,
                       k1b, k2b, vt1, vt2);
    hipLaunchKernelGGL(kd_sub, dim3(2048), dim3(256), 0, stream, k1b, k2b, kd);
    hipLaunchKernelGGL(ebd_k, dim3(8), dim3(256), 0, stream, kd, bq1, bq2, ebd);
    hipLaunchKernelGGL(gemm_gkk, dim3(2, 8, 32), dim3(64), 0, stream,
                       kd, wq1t, wq2t, kkd1, kkd2);
    hipLaunchKernelGGL(fused_attn, dim3(512), dim3(256), 0, stream,
                       x1, x2, kkd1, kkd2, vt1, vt2, ebd, scale, out1, out2);
}